// Round 15
// baseline (290.798 us; speedup 1.0000x reference)
//
#include <hip/hip_runtime.h>
#include <hip/hip_bf16.h>
#include <math.h>

#define PI_F 3.14159265358979323846f

// ---------------------------------------------------------------------------
// x (8,64,256,256) f32; weight_fft (64,64,256,129) f32; bias (64) f32
// y (8,64,256,256) f32.
// Xf workspace: complex packed-bf16, [bo][n], n = h*129+w, 512 x 33024 x 4B
// (67.6 MB -> L3-resident). All arithmetic fp32; inter-pass storage bf16.
// Round-15: single delta vs rd14 — K2 block 256 -> 512 threads on the same
// 32-bin tile (each thread 4 i instead of 8; acc[4][8]=64 VGPR). LDS still
// 64 KB -> 2 blocks/CU -> 4 waves/SIMD (2x TLP for latency hiding). W still
// read exactly once; per-output accumulation order unchanged (bit-identical).
// ---------------------------------------------------------------------------

#define NWACT 15   // FFT-active waves in ROW phases (tiles); col phase uses 16

__device__ __forceinline__ unsigned pack_bf(float re, float im) {
    unsigned ur = __float_as_uint(re);
    unsigned ui = __float_as_uint(im);
    ur = (ur + 0x7fffu + ((ur >> 16) & 1u)) >> 16;     // RNE to bf16
    ui = (ui + 0x7fffu + ((ui >> 16) & 1u)) & 0xffff0000u;
    return ur | ui;
}
__device__ __forceinline__ float2 unpack_bf(unsigned p) {
    return make_float2(__uint_as_float(p << 16),
                       __uint_as_float(p & 0xffff0000u));
}

// work-tile swizzle (row phases): spreads b64 accesses over bank pairs
__device__ __forceinline__ int s2i(int p) { return p ^ (((p >> 4) & 3) << 2); }

__device__ __forceinline__ float2 cadd(float2 a, float2 b){ return make_float2(a.x+b.x, a.y+b.y); }
__device__ __forceinline__ float2 csub(float2 a, float2 b){ return make_float2(a.x-b.x, a.y-b.y); }
__device__ __forceinline__ float2 cmul(float2 a, float2 b){ return make_float2(a.x*b.x-a.y*b.y, a.x*b.y+a.y*b.x); }

// ------------------------- row-phase FFT machinery --------------------------
template<int SGN>
__device__ __forceinline__ void mk_tw(int jt, float invh, float2& w1, float2& w2) {
    const float th = (SGN < 0 ? -PI_F : PI_F) * (float)jt * invh;
    __sincosf(th, &w1.y, &w1.x);
    __sincosf(0.5f * th, &w2.y, &w2.x);
}

template<int SGN>
__device__ __forceinline__ void quad2(float2& u0, float2& u1, float2& u2, float2& u3,
                                      float2 w1, float2 w2) {
    const float2 t1 = cmul(w1, u1), t3 = cmul(w1, u3);
    const float2 v0 = cadd(u0, t1), v1 = csub(u0, t1);
    const float2 v2 = cadd(u2, t3), v3 = csub(u2, t3);
    const float2 t2 = cmul(w2, v2);
    float2 t4 = cmul(w2, v3);
    t4 = (SGN < 0) ? make_float2(t4.y, -t4.x) : make_float2(-t4.y, t4.x);
    u0 = cadd(v0, t2); u2 = csub(v0, t2);
    u1 = cadd(v1, t4); u3 = csub(v1, t4);
}

// rd12 row FFT: inputs staged in LDS work tile (natural order, s2i-swizzled).
template<int SGN>
__device__ __forceinline__ void fft256(float2* w, int j, const float2* tw,
                                       float2& o0, float2& o1, float2& o2, float2& o3) {
    const int r = (int)(__brev((unsigned)j) >> 26);           // brev6
    float2 u0 = w[s2i(r)], u1 = w[s2i(r + 128)], u2 = w[s2i(r + 64)], u3 = w[s2i(r + 192)];
    __builtin_amdgcn_wave_barrier();
    {
        const float2 v0 = cadd(u0, u1), v1 = csub(u0, u1);
        const float2 v2 = cadd(u2, u3), v3 = csub(u2, u3);
        const float2 t4 = (SGN < 0) ? make_float2(v3.y, -v3.x) : make_float2(-v3.y, v3.x);
        u0 = cadd(v0, v2); u2 = csub(v0, v2);
        u1 = cadd(v1, t4); u3 = csub(v1, t4);
    }
    const int p4 = s2i(4 * j);
    *(float4*)&w[p4]     = make_float4(u0.x, u0.y, u1.x, u1.y);
    *(float4*)&w[p4 + 2] = make_float4(u2.x, u2.y, u3.x, u3.y);
    __builtin_amdgcn_wave_barrier();
    {
        const int p = ((j >> 2) << 4) | (j & 3);
        float2 a0 = w[s2i(p)], a1 = w[s2i(p+4)], a2 = w[s2i(p+8)], a3 = w[s2i(p+12)];
        quad2<SGN>(a0, a1, a2, a3, tw[0], tw[1]);
        w[s2i(p)] = a0; w[s2i(p+4)] = a1; w[s2i(p+8)] = a2; w[s2i(p+12)] = a3;
    }
    __builtin_amdgcn_wave_barrier();
    {
        const int p = ((j >> 4) << 6) | (j & 15);
        float2 a0 = w[s2i(p)], a1 = w[s2i(p+16)], a2 = w[s2i(p+32)], a3 = w[s2i(p+48)];
        quad2<SGN>(a0, a1, a2, a3, tw[2], tw[3]);
        w[s2i(p)] = a0; w[s2i(p+16)] = a1; w[s2i(p+32)] = a2; w[s2i(p+48)] = a3;
    }
    __builtin_amdgcn_wave_barrier();
    {
        float2 a0 = w[s2i(j)], a1 = w[s2i(j+64)], a2 = w[s2i(j+128)], a3 = w[s2i(j+192)];
        quad2<SGN>(a0, a1, a2, a3, tw[4], tw[5]);
        o0 = a0; o1 = a1; o2 = a2; o3 = a3;
    }
}

// rd13-verified variant: round-1 inputs supplied in registers
// (u0=z(r), u1=z(r+128), u2=z(r+64), u3=z(r+192), r=brev6(j)).
template<int SGN>
__device__ __forceinline__ void fft256_reg(float2* w, int j, const float2* tw,
                                           float2 u0, float2 u1, float2 u2, float2 u3,
                                           float2& o0, float2& o1, float2& o2, float2& o3) {
    {
        const float2 v0 = cadd(u0, u1), v1 = csub(u0, u1);
        const float2 v2 = cadd(u2, u3), v3 = csub(u2, u3);
        const float2 t4 = (SGN < 0) ? make_float2(v3.y, -v3.x) : make_float2(-v3.y, v3.x);
        u0 = cadd(v0, v2); u2 = csub(v0, v2);
        u1 = cadd(v1, t4); u3 = csub(v1, t4);
    }
    __builtin_amdgcn_wave_barrier();                 // prior r4 reads before writes
    const int p4 = s2i(4 * j);
    *(float4*)&w[p4]     = make_float4(u0.x, u0.y, u1.x, u1.y);
    *(float4*)&w[p4 + 2] = make_float4(u2.x, u2.y, u3.x, u3.y);
    __builtin_amdgcn_wave_barrier();
    {
        const int p = ((j >> 2) << 4) | (j & 3);
        float2 a0 = w[s2i(p)], a1 = w[s2i(p+4)], a2 = w[s2i(p+8)], a3 = w[s2i(p+12)];
        quad2<SGN>(a0, a1, a2, a3, tw[0], tw[1]);
        w[s2i(p)] = a0; w[s2i(p+4)] = a1; w[s2i(p+8)] = a2; w[s2i(p+12)] = a3;
    }
    __builtin_amdgcn_wave_barrier();
    {
        const int p = ((j >> 4) << 6) | (j & 15);
        float2 a0 = w[s2i(p)], a1 = w[s2i(p+16)], a2 = w[s2i(p+32)], a3 = w[s2i(p+48)];
        quad2<SGN>(a0, a1, a2, a3, tw[2], tw[3]);
        w[s2i(p)] = a0; w[s2i(p+16)] = a1; w[s2i(p+32)] = a2; w[s2i(p+48)] = a3;
    }
    __builtin_amdgcn_wave_barrier();
    {
        float2 a0 = w[s2i(j)], a1 = w[s2i(j+64)], a2 = w[s2i(j+128)], a3 = w[s2i(j+192)];
        quad2<SGN>(a0, a1, a2, a3, tw[4], tw[5]);
        o0 = a0; o1 = a1; o2 = a2; o3 = a3;
    }
}

// ------------------------- col-phase radix-16 machinery ---------------------
template<int SGN>
__device__ __forceinline__ void dft4(float2& u0, float2& u1, float2& u2, float2& u3) {
    const float2 t0 = cadd(u0, u2), t1 = csub(u0, u2);
    const float2 t2 = cadd(u1, u3), t3 = csub(u1, u3);
    const float2 t3i = (SGN < 0) ? make_float2(t3.y, -t3.x) : make_float2(-t3.y, t3.x);
    u0 = cadd(t0, t2); u1 = cadd(t1, t3i);
    u2 = csub(t0, t2); u3 = csub(t1, t3i);
}

template<int SGN>
__device__ __forceinline__ void dft16(float2 x[16]) {
#pragma unroll
    for (int b = 0; b < 4; ++b) dft4<SGN>(x[b], x[b+4], x[b+8], x[b+12]);
    const float sg = (SGN < 0) ? -1.0f : 1.0f;
    const float C8 = 0.9238795325112867f, S8 = 0.3826834323650898f, H = 0.7071067811865476f;
    x[5]  = cmul(x[5],  make_float2(C8,  sg*S8));
    x[6]  = cmul(x[6],  make_float2(H,   sg*H));
    x[7]  = cmul(x[7],  make_float2(S8,  sg*C8));
    x[9]  = cmul(x[9],  make_float2(H,   sg*H));
    x[10] = (SGN < 0) ? make_float2(x[10].y, -x[10].x)
                      : make_float2(-x[10].y, x[10].x);
    x[11] = cmul(x[11], make_float2(-H,  sg*H));
    x[13] = cmul(x[13], make_float2(S8,  sg*C8));
    x[14] = cmul(x[14], make_float2(-H,  sg*H));
    x[15] = cmul(x[15], make_float2(-C8, -sg*S8));
#pragma unroll
    for (int k1 = 0; k1 < 4; ++k1) dft4<SGN>(x[4*k1], x[4*k1+1], x[4*k1+2], x[4*k1+3]);
}

template<int SGN>
__device__ __forceinline__ void colfft16(unsigned* __restrict__ S, int l, int c, bool act) {
    float2 x[16];
    if (act) {
#pragma unroll
        for (int r = 0; r < 16; ++r) x[r] = unpack_bf(S[(16*r + l)*129 + c]);
    } else {
#pragma unroll
        for (int r = 0; r < 16; ++r) x[r] = make_float2(0.0f, 0.0f);
    }
    dft16<SGN>(x);
    float2 twl;
    {
        const float th = (SGN < 0 ? -1.0f : 1.0f) * (2.0f * PI_F / 256.0f) * (float)l;
        __sincosf(th, &twl.y, &twl.x);
    }
    float2 t = twl;
#pragma unroll
    for (int kk = 1; kk < 16; ++kk) {
        const int r = 4*(kk & 3) + (kk >> 2);
        x[r] = cmul(x[r], t);
        if (kk < 15) t = cmul(t, twl);
    }
    if (act) {
#pragma unroll
        for (int kk = 0; kk < 16; ++kk) {
            const int r = 4*(kk & 3) + (kk >> 2);
            S[(16*kk + (l ^ kk))*129 + c] = pack_bf(x[r].x, x[r].y);
        }
    }
    __builtin_amdgcn_wave_barrier();
    if (act) {
#pragma unroll
        for (int n2 = 0; n2 < 16; ++n2) x[n2] = unpack_bf(S[(16*l + (n2 ^ l))*129 + c]);
    }
    dft16<SGN>(x);
    if (act) {
#pragma unroll
        for (int r = 0; r < 16; ++r) {
            const int kk = 4*(r & 3) + (r >> 2);   // final k = 16*kk + l
            S[(16*kk + l)*129 + c] = pack_bf(x[r].x, x[r].y);
        }
    }
    __builtin_amdgcn_wave_barrier();
}

#define SMEM_BYTES (132096 + NWACT * 256 * 8)   // S (33024 u32) + 15 row tiles

// ------------------- K1: fused row-rFFT + col-FFT per image (rd12) ----------
__global__ __launch_bounds__(1024) void k_fwd2d(const float* __restrict__ x,
                                                unsigned* __restrict__ Xf) {
    extern __shared__ char smem[];
    unsigned* S = (unsigned*)smem;
    float2* w = (float2*)(smem + 132096) + ((threadIdx.x >> 6) << 8);
    const int t = threadIdx.x, f = t >> 6, j = t & 63;
    const int bo = blockIdx.x;
    const float* xi = x + (size_t)bo * 65536;

    float2 tw[6];
    mk_tw<-1>(j & 3,  0.25f,       tw[0], tw[1]);
    mk_tw<-1>(j & 15, 1.0f/16.0f,  tw[2], tw[3]);
    mk_tw<-1>(j,      1.0f/64.0f,  tw[4], tw[5]);

    // row phase (paired, waves 0..14): float4-staged loads (rd12)
    if (f < NWACT) {
        for (int rp = f; rp < 128; rp += NWACT) {
            const int r1 = rp, r2 = rp + 128;
            const float4 va = ((const float4*)(xi + (r1 << 8)))[j];
            const float4 vb = ((const float4*)(xi + (r2 << 8)))[j];
            const int p4 = s2i(4 * j);
            *(float4*)&w[p4]     = make_float4(va.x, vb.x, va.y, vb.y);
            *(float4*)&w[p4 + 2] = make_float4(va.z, vb.z, va.w, vb.w);
            __builtin_amdgcn_wave_barrier();
            float2 o0, o1, o2, o3;
            fft256<-1>(w, j, tw, o0, o1, o2, o3);
            const int src = (64 - j) & 63;
            float2 P3, P2;
            P3.x = __shfl(o3.x, src); P3.y = __shfl(o3.y, src);   // Z[256-j]
            P2.x = __shfl(o2.x, src); P2.y = __shfl(o2.y, src);   // Z[192-j]
            const float2 Cj = (j == 0) ? make_float2(o0.x, -o0.y)
                                       : make_float2(P3.x, -P3.y);
            const float2 Ck = (j == 0) ? make_float2(P3.x, -P3.y)
                                       : make_float2(P2.x, -P2.y);
            const float2 Aj = make_float2(0.5f * (o0.x + Cj.x), 0.5f * (o0.y + Cj.y));
            const float2 Bj = make_float2(0.5f * (o0.y - Cj.y), -0.5f * (o0.x - Cj.x));
            const float2 Ak = make_float2(0.5f * (o1.x + Ck.x), 0.5f * (o1.y + Ck.y));
            const float2 Bk = make_float2(0.5f * (o1.y - Ck.y), -0.5f * (o1.x - Ck.x));
            S[r1 * 129 + j]      = pack_bf(Aj.x, Aj.y);
            S[r1 * 129 + 64 + j] = pack_bf(Ak.x, Ak.y);
            S[r2 * 129 + j]      = pack_bf(Bj.x, Bj.y);
            S[r2 * 129 + 64 + j] = pack_bf(Bk.x, Bk.y);
            if (j == 0) {
                S[r1 * 129 + 128] = pack_bf(o2.x, 0.0f);
                S[r2 * 129 + 128] = pack_bf(o2.y, 0.0f);
            }
            __builtin_amdgcn_wave_barrier();
        }
    }
    __syncthreads();
    // col phase (radix-16, all 16 waves, 4 cols/wave, cols 16 apart)
    {
        const int g4 = (t >> 4) & 3, l16 = t & 15;
        for (int T = f; T < 33; T += 16) {
            const int cb = (T < 16) ? T : ((T < 32) ? T + 48 : 128);
            const int c = cb + 16 * g4;
            const bool act = (T < 32) || (g4 == 0);
            colfft16<-1>(S, l16, c, act);
        }
    }
    __syncthreads();
    // dump S -> Xf[bo]
    uint4* dst = (uint4*)(Xf + (size_t)bo * 33024);
    const uint4* src4 = (const uint4*)S;
    for (int e = t; e < 8256; e += 1024) dst[e] = src4[e];
}

// --------------------- K2: per-bin einsum (in-place, 512 thr) ---------------
// Z[b,i,n] = sum_o X[b,o,n] * W[o,i,n], n flat = h*129+w. Block = 32 n (one
// 128B line). 512 threads: thread (nl, j=t>>5 in 0..15) owns i = (r<<4)|j,
// r<4. LDS 64 KB -> 2 blocks/CU -> 4 waves/SIMD (2x TLP vs rd14). W still
// read exactly once; depth-2 clamped register prefetch kept.
__global__ __launch_bounds__(512) void k_einsum(unsigned* __restrict__ Xf,
                                                const float* __restrict__ Wt) {
    __shared__ unsigned xs[512][32];            // [(b<<6)|o][nl] = 64 KB
    const int t = threadIdx.x;
    const int bid = blockIdx.x;                 // 1032 = 8 XCD x 129
    const int nid = (bid & 7) * 129 + (bid >> 3);
    const size_t n0 = (size_t)nid * 32;

#pragma unroll
    for (int k = 0; k < 8; ++k) {
        const int e = t + 512 * k;              // 4096 uint4 = 512 rows x 32 u32
        const int pr = e >> 3, q = e & 7;
        const uint4 v = *reinterpret_cast<const uint4*>(
            Xf + (size_t)pr * 33024 + n0 + (q << 2));
        *reinterpret_cast<uint4*>(&xs[pr][q << 2]) = v;
    }
    __syncthreads();

    const int nl = t & 31, j = t >> 5;          // j in 0..15
    float2 acc[4][8];
#pragma unroll
    for (int r = 0; r < 4; ++r)
#pragma unroll
        for (int b = 0; b < 8; ++b) acc[r][b] = make_float2(0.0f, 0.0f);

    const float* Wb = Wt + n0 + nl;
    auto wload = [&](int o, float (&buf)[4]) {
#pragma unroll
        for (int r = 0; r < 4; ++r)
            buf[r] = __builtin_nontemporal_load(
                Wb + (size_t)((o << 6) | ((r << 4) | j)) * 33024);
    };
    auto fmab = [&](int o, const float (&wc)[4]) {
        float2 xv[8];
#pragma unroll
        for (int b = 0; b < 8; ++b) xv[b] = unpack_bf(xs[(b << 6) | o][nl]);
#pragma unroll
        for (int r = 0; r < 4; ++r)
#pragma unroll
            for (int b = 0; b < 8; ++b) {
                acc[r][b].x += xv[b].x * wc[r];
                acc[r][b].y += xv[b].y * wc[r];
            }
    };

    float wA[4], wB[4];
    wload(0, wA);
    wload(1, wB);
    for (int o = 0; o < 64; o += 2) {
        float wc0[4];
#pragma unroll
        for (int r = 0; r < 4; ++r) wc0[r] = wA[r];
        wload(min(o + 2, 63), wA);              // clamped prefetch (tail re-read is L2-hot)
        fmab(o, wc0);
        float wc1[4];
#pragma unroll
        for (int r = 0; r < 4; ++r) wc1[r] = wB[r];
        wload(min(o + 3, 63), wB);
        fmab(o + 1, wc1);
    }

#pragma unroll
    for (int r = 0; r < 4; ++r) {
        const int i = (r << 4) | j;
#pragma unroll
        for (int b = 0; b < 8; ++b) {
            Xf[(size_t)((b << 6) | i) * 33024 + n0 + nl] =
                pack_bf(acc[r][b].x, acc[r][b].y);
        }
    }
}

// ------------- K3: fused col-iFFT + row-irFFT (+bias) per image -------------
__global__ __launch_bounds__(1024) void k_inv2d(const unsigned* __restrict__ Xf,
                                                const float* __restrict__ bias,
                                                float* __restrict__ y) {
    extern __shared__ char smem[];
    unsigned* S = (unsigned*)smem;
    float2* w = (float2*)(smem + 132096) + ((threadIdx.x >> 6) << 8);
    const int t = threadIdx.x, f = t >> 6, j = t & 63;
    const int bo = blockIdx.x;
    const float bv = bias[bo & 63];

    float2 tw[6];
    mk_tw<+1>(j & 3,  0.25f,       tw[0], tw[1]);
    mk_tw<+1>(j & 15, 1.0f/16.0f,  tw[2], tw[3]);
    mk_tw<+1>(j,      1.0f/64.0f,  tw[4], tw[5]);

    const int rbr = (int)(__brev((unsigned)j) >> 26);    // brev6(j)

    // load Xf[bo] -> S
    {
        uint4* s4 = (uint4*)S;
        const uint4* g4p = (const uint4*)(Xf + (size_t)bo * 33024);
        for (int e = t; e < 8256; e += 1024) s4[e] = g4p[e];
    }
    __syncthreads();
    // col inverse phase (radix-16, all 16 waves)
    {
        const int g4 = (t >> 4) & 3, l16 = t & 15;
        for (int T = f; T < 33; T += 16) {
            const int cb = (T < 16) ? T : ((T < 32) ? T + 48 : 128);
            const int c = cb + 16 * g4;
            const bool act = (T < 32) || (g4 == 0);
            colfft16<+1>(S, l16, c, act);
        }
    }
    __syncthreads();
    // row inverse phase (paired, waves 0..14): rd13-verified register-fed
    // round 1 — z built at bit-reversed base m straight from S; k=0,128
    // projected to Re (reference irfft discards their imag content).
    float* yo = y + (size_t)bo * 65536;
    if (f < NWACT) {
        for (int rp = f; rp < 128; rp += NWACT) {
            const int r1 = rp, r2 = rp + 128;
            const unsigned* Sa = S + r1 * 129;
            const unsigned* Sb = S + r2 * 129;
            const int m = rbr;
            const float2 A0 = unpack_bf(Sa[m]),      B0 = unpack_bf(Sb[m]);
            const float2 A1 = unpack_bf(Sa[m + 64]), B1 = unpack_bf(Sb[m + 64]);
            const int i2 = (m == 0) ? 128 : 128 - m;
            const float2 A2 = unpack_bf(Sa[i2]),     B2 = unpack_bf(Sb[i2]);
            const float2 A3 = unpack_bf(Sa[64 - m]), B3 = unpack_bf(Sb[64 - m]);
            // u0 = z(m), u1 = z(m+128), u2 = z(m+64), u3 = z(m+192)
            const float2 u0 = (m == 0)
                ? make_float2(A0.x, B0.x)                                 // k=0 projected
                : make_float2(A0.x - B0.y, A0.y + B0.x);                  // direct
            const float2 u1 = (m == 0)
                ? make_float2(A2.x, B2.x)                                 // k=128 projected
                : make_float2(A2.x + B2.y, B2.x - A2.y);                  // reflected
            const float2 u2 = make_float2(A1.x - B1.y, A1.y + B1.x);      // k=m+64 direct
            const float2 u3 = make_float2(A3.x + B3.y, B3.x - A3.y);      // k=m+192 reflected
            float2 o0, o1, o2, o3;
            fft256_reg<+1>(w, j, tw, u0, u1, u2, u3, o0, o1, o2, o3);
            const float sc = 1.0f / 65536.0f;
            float* y1 = yo + (r1 << 8);
            float* y2 = yo + (r2 << 8);
            __builtin_nontemporal_store(o0.x * sc + bv, y1 + j);
            __builtin_nontemporal_store(o1.x * sc + bv, y1 + j + 64);
            __builtin_nontemporal_store(o2.x * sc + bv, y1 + j + 128);
            __builtin_nontemporal_store(o3.x * sc + bv, y1 + j + 192);
            __builtin_nontemporal_store(o0.y * sc + bv, y2 + j);
            __builtin_nontemporal_store(o1.y * sc + bv, y2 + j + 64);
            __builtin_nontemporal_store(o2.y * sc + bv, y2 + j + 128);
            __builtin_nontemporal_store(o3.y * sc + bv, y2 + j + 192);
            __builtin_amdgcn_wave_barrier();
        }
    }
}

// ---------------------------------------------------------------------------
extern "C" void kernel_launch(void* const* d_in, const int* in_sizes, int n_in,
                              void* d_out, int out_size, void* d_ws,
                              size_t ws_size, hipStream_t stream) {
    (void)in_sizes; (void)n_in; (void)out_size; (void)ws_size;
    const float* x    = (const float*)d_in[0];
    const float* wfft = (const float*)d_in[1];
    const float* bias = (const float*)d_in[2];
    float* y = (float*)d_out;
    unsigned* Xf = (unsigned*)d_ws;             // 512 x 33024 uint = 67.6 MB

    hipFuncSetAttribute((const void*)k_fwd2d,
                        hipFuncAttributeMaxDynamicSharedMemorySize, SMEM_BYTES);
    hipFuncSetAttribute((const void*)k_inv2d,
                        hipFuncAttributeMaxDynamicSharedMemorySize, SMEM_BYTES);

    k_fwd2d<<<512, 1024, SMEM_BYTES, stream>>>(x, Xf);
    k_einsum<<<1032, 512, 0, stream>>>(Xf, wfft);
    k_inv2d<<<512, 1024, SMEM_BYTES, stream>>>(Xf, bias, y);
}

// Round 17
// 271.487 us; speedup vs baseline: 1.0711x; 1.0711x over previous
//
#include <hip/hip_runtime.h>
#include <hip/hip_bf16.h>
#include <math.h>

#define PI_F 3.14159265358979323846f

// ---------------------------------------------------------------------------
// x (8,64,256,256) f32; weight_fft (64,64,256,129) f32; bias (64) f32
// y (8,64,256,256) f32.
// Xf workspace: complex packed-bf16, [bo][n], n = h*129+w, 512 x 33024 x 4B
// (67.6 MB -> L3-resident). All arithmetic fp32; inter-pass storage bf16.
// Round-17 (= rd16 fixed): K2 inner product as v_pk_fma_f32 with proper
// 64-bit pair operands (wp[r] = {w,w} materialized once per o-iter; VOP3P
// requires pair-aligned sources — rd16's op_sel_hi scalar src0 didn't
// assemble). 128 scalar FMA -> 64 pk-FMA + 8 packs per o-iter. Bit-identical.
// ---------------------------------------------------------------------------

#define NWACT 15   // FFT-active waves in ROW phases (tiles); col phase uses 16

typedef float f32x2 __attribute__((ext_vector_type(2)));

__device__ __forceinline__ unsigned pack_bf(float re, float im) {
    unsigned ur = __float_as_uint(re);
    unsigned ui = __float_as_uint(im);
    ur = (ur + 0x7fffu + ((ur >> 16) & 1u)) >> 16;     // RNE to bf16
    ui = (ui + 0x7fffu + ((ui >> 16) & 1u)) & 0xffff0000u;
    return ur | ui;
}
__device__ __forceinline__ float2 unpack_bf(unsigned p) {
    return make_float2(__uint_as_float(p << 16),
                       __uint_as_float(p & 0xffff0000u));
}

// work-tile swizzle (row phases): spreads b64 accesses over bank pairs
__device__ __forceinline__ int s2i(int p) { return p ^ (((p >> 4) & 3) << 2); }

__device__ __forceinline__ float2 cadd(float2 a, float2 b){ return make_float2(a.x+b.x, a.y+b.y); }
__device__ __forceinline__ float2 csub(float2 a, float2 b){ return make_float2(a.x-b.x, a.y-b.y); }
__device__ __forceinline__ float2 cmul(float2 a, float2 b){ return make_float2(a.x*b.x-a.y*b.y, a.x*b.y+a.y*b.x); }

// ------------------------- row-phase FFT machinery --------------------------
template<int SGN>
__device__ __forceinline__ void mk_tw(int jt, float invh, float2& w1, float2& w2) {
    const float th = (SGN < 0 ? -PI_F : PI_F) * (float)jt * invh;
    __sincosf(th, &w1.y, &w1.x);
    __sincosf(0.5f * th, &w2.y, &w2.x);
}

template<int SGN>
__device__ __forceinline__ void quad2(float2& u0, float2& u1, float2& u2, float2& u3,
                                      float2 w1, float2 w2) {
    const float2 t1 = cmul(w1, u1), t3 = cmul(w1, u3);
    const float2 v0 = cadd(u0, t1), v1 = csub(u0, t1);
    const float2 v2 = cadd(u2, t3), v3 = csub(u2, t3);
    const float2 t2 = cmul(w2, v2);
    float2 t4 = cmul(w2, v3);
    t4 = (SGN < 0) ? make_float2(t4.y, -t4.x) : make_float2(-t4.y, t4.x);
    u0 = cadd(v0, t2); u2 = csub(v0, t2);
    u1 = cadd(v1, t4); u3 = csub(v1, t4);
}

// rd12 row FFT: inputs staged in LDS work tile (natural order, s2i-swizzled).
template<int SGN>
__device__ __forceinline__ void fft256(float2* w, int j, const float2* tw,
                                       float2& o0, float2& o1, float2& o2, float2& o3) {
    const int r = (int)(__brev((unsigned)j) >> 26);           // brev6
    float2 u0 = w[s2i(r)], u1 = w[s2i(r + 128)], u2 = w[s2i(r + 64)], u3 = w[s2i(r + 192)];
    __builtin_amdgcn_wave_barrier();
    {
        const float2 v0 = cadd(u0, u1), v1 = csub(u0, u1);
        const float2 v2 = cadd(u2, u3), v3 = csub(u2, u3);
        const float2 t4 = (SGN < 0) ? make_float2(v3.y, -v3.x) : make_float2(-v3.y, v3.x);
        u0 = cadd(v0, v2); u2 = csub(v0, v2);
        u1 = cadd(v1, t4); u3 = csub(v1, t4);
    }
    const int p4 = s2i(4 * j);
    *(float4*)&w[p4]     = make_float4(u0.x, u0.y, u1.x, u1.y);
    *(float4*)&w[p4 + 2] = make_float4(u2.x, u2.y, u3.x, u3.y);
    __builtin_amdgcn_wave_barrier();
    {
        const int p = ((j >> 2) << 4) | (j & 3);
        float2 a0 = w[s2i(p)], a1 = w[s2i(p+4)], a2 = w[s2i(p+8)], a3 = w[s2i(p+12)];
        quad2<SGN>(a0, a1, a2, a3, tw[0], tw[1]);
        w[s2i(p)] = a0; w[s2i(p+4)] = a1; w[s2i(p+8)] = a2; w[s2i(p+12)] = a3;
    }
    __builtin_amdgcn_wave_barrier();
    {
        const int p = ((j >> 4) << 6) | (j & 15);
        float2 a0 = w[s2i(p)], a1 = w[s2i(p+16)], a2 = w[s2i(p+32)], a3 = w[s2i(p+48)];
        quad2<SGN>(a0, a1, a2, a3, tw[2], tw[3]);
        w[s2i(p)] = a0; w[s2i(p+16)] = a1; w[s2i(p+32)] = a2; w[s2i(p+48)] = a3;
    }
    __builtin_amdgcn_wave_barrier();
    {
        float2 a0 = w[s2i(j)], a1 = w[s2i(j+64)], a2 = w[s2i(j+128)], a3 = w[s2i(j+192)];
        quad2<SGN>(a0, a1, a2, a3, tw[4], tw[5]);
        o0 = a0; o1 = a1; o2 = a2; o3 = a3;
    }
}

// rd13-verified variant: round-1 inputs supplied in registers
// (u0=z(r), u1=z(r+128), u2=z(r+64), u3=z(r+192), r=brev6(j)).
template<int SGN>
__device__ __forceinline__ void fft256_reg(float2* w, int j, const float2* tw,
                                           float2 u0, float2 u1, float2 u2, float2 u3,
                                           float2& o0, float2& o1, float2& o2, float2& o3) {
    {
        const float2 v0 = cadd(u0, u1), v1 = csub(u0, u1);
        const float2 v2 = cadd(u2, u3), v3 = csub(u2, u3);
        const float2 t4 = (SGN < 0) ? make_float2(v3.y, -v3.x) : make_float2(-v3.y, v3.x);
        u0 = cadd(v0, v2); u2 = csub(v0, v2);
        u1 = cadd(v1, t4); u3 = csub(v1, t4);
    }
    __builtin_amdgcn_wave_barrier();                 // prior r4 reads before writes
    const int p4 = s2i(4 * j);
    *(float4*)&w[p4]     = make_float4(u0.x, u0.y, u1.x, u1.y);
    *(float4*)&w[p4 + 2] = make_float4(u2.x, u2.y, u3.x, u3.y);
    __builtin_amdgcn_wave_barrier();
    {
        const int p = ((j >> 2) << 4) | (j & 3);
        float2 a0 = w[s2i(p)], a1 = w[s2i(p+4)], a2 = w[s2i(p+8)], a3 = w[s2i(p+12)];
        quad2<SGN>(a0, a1, a2, a3, tw[0], tw[1]);
        w[s2i(p)] = a0; w[s2i(p+4)] = a1; w[s2i(p+8)] = a2; w[s2i(p+12)] = a3;
    }
    __builtin_amdgcn_wave_barrier();
    {
        const int p = ((j >> 4) << 6) | (j & 15);
        float2 a0 = w[s2i(p)], a1 = w[s2i(p+16)], a2 = w[s2i(p+32)], a3 = w[s2i(p+48)];
        quad2<SGN>(a0, a1, a2, a3, tw[2], tw[3]);
        w[s2i(p)] = a0; w[s2i(p+16)] = a1; w[s2i(p+32)] = a2; w[s2i(p+48)] = a3;
    }
    __builtin_amdgcn_wave_barrier();
    {
        float2 a0 = w[s2i(j)], a1 = w[s2i(j+64)], a2 = w[s2i(j+128)], a3 = w[s2i(j+192)];
        quad2<SGN>(a0, a1, a2, a3, tw[4], tw[5]);
        o0 = a0; o1 = a1; o2 = a2; o3 = a3;
    }
}

// ------------------------- col-phase radix-16 machinery ---------------------
template<int SGN>
__device__ __forceinline__ void dft4(float2& u0, float2& u1, float2& u2, float2& u3) {
    const float2 t0 = cadd(u0, u2), t1 = csub(u0, u2);
    const float2 t2 = cadd(u1, u3), t3 = csub(u1, u3);
    const float2 t3i = (SGN < 0) ? make_float2(t3.y, -t3.x) : make_float2(-t3.y, t3.x);
    u0 = cadd(t0, t2); u1 = cadd(t1, t3i);
    u2 = csub(t0, t2); u3 = csub(t1, t3i);
}

template<int SGN>
__device__ __forceinline__ void dft16(float2 x[16]) {
#pragma unroll
    for (int b = 0; b < 4; ++b) dft4<SGN>(x[b], x[b+4], x[b+8], x[b+12]);
    const float sg = (SGN < 0) ? -1.0f : 1.0f;
    const float C8 = 0.9238795325112867f, S8 = 0.3826834323650898f, H = 0.7071067811865476f;
    x[5]  = cmul(x[5],  make_float2(C8,  sg*S8));
    x[6]  = cmul(x[6],  make_float2(H,   sg*H));
    x[7]  = cmul(x[7],  make_float2(S8,  sg*C8));
    x[9]  = cmul(x[9],  make_float2(H,   sg*H));
    x[10] = (SGN < 0) ? make_float2(x[10].y, -x[10].x)
                      : make_float2(-x[10].y, x[10].x);
    x[11] = cmul(x[11], make_float2(-H,  sg*H));
    x[13] = cmul(x[13], make_float2(S8,  sg*C8));
    x[14] = cmul(x[14], make_float2(-H,  sg*H));
    x[15] = cmul(x[15], make_float2(-C8, -sg*S8));
#pragma unroll
    for (int k1 = 0; k1 < 4; ++k1) dft4<SGN>(x[4*k1], x[4*k1+1], x[4*k1+2], x[4*k1+3]);
}

template<int SGN>
__device__ __forceinline__ void colfft16(unsigned* __restrict__ S, int l, int c, bool act) {
    float2 x[16];
    if (act) {
#pragma unroll
        for (int r = 0; r < 16; ++r) x[r] = unpack_bf(S[(16*r + l)*129 + c]);
    } else {
#pragma unroll
        for (int r = 0; r < 16; ++r) x[r] = make_float2(0.0f, 0.0f);
    }
    dft16<SGN>(x);
    float2 twl;
    {
        const float th = (SGN < 0 ? -1.0f : 1.0f) * (2.0f * PI_F / 256.0f) * (float)l;
        __sincosf(th, &twl.y, &twl.x);
    }
    float2 t = twl;
#pragma unroll
    for (int kk = 1; kk < 16; ++kk) {
        const int r = 4*(kk & 3) + (kk >> 2);
        x[r] = cmul(x[r], t);
        if (kk < 15) t = cmul(t, twl);
    }
    if (act) {
#pragma unroll
        for (int kk = 0; kk < 16; ++kk) {
            const int r = 4*(kk & 3) + (kk >> 2);
            S[(16*kk + (l ^ kk))*129 + c] = pack_bf(x[r].x, x[r].y);
        }
    }
    __builtin_amdgcn_wave_barrier();
    if (act) {
#pragma unroll
        for (int n2 = 0; n2 < 16; ++n2) x[n2] = unpack_bf(S[(16*l + (n2 ^ l))*129 + c]);
    }
    dft16<SGN>(x);
    if (act) {
#pragma unroll
        for (int r = 0; r < 16; ++r) {
            const int kk = 4*(r & 3) + (r >> 2);   // final k = 16*kk + l
            S[(16*kk + l)*129 + c] = pack_bf(x[r].x, x[r].y);
        }
    }
    __builtin_amdgcn_wave_barrier();
}

#define SMEM_BYTES (132096 + NWACT * 256 * 8)   // S (33024 u32) + 15 row tiles

// ------------------- K1: fused row-rFFT + col-FFT per image (rd12) ----------
__global__ __launch_bounds__(1024) void k_fwd2d(const float* __restrict__ x,
                                                unsigned* __restrict__ Xf) {
    extern __shared__ char smem[];
    unsigned* S = (unsigned*)smem;
    float2* w = (float2*)(smem + 132096) + ((threadIdx.x >> 6) << 8);
    const int t = threadIdx.x, f = t >> 6, j = t & 63;
    const int bo = blockIdx.x;
    const float* xi = x + (size_t)bo * 65536;

    float2 tw[6];
    mk_tw<-1>(j & 3,  0.25f,       tw[0], tw[1]);
    mk_tw<-1>(j & 15, 1.0f/16.0f,  tw[2], tw[3]);
    mk_tw<-1>(j,      1.0f/64.0f,  tw[4], tw[5]);

    // row phase (paired, waves 0..14): float4-staged loads (rd12)
    if (f < NWACT) {
        for (int rp = f; rp < 128; rp += NWACT) {
            const int r1 = rp, r2 = rp + 128;
            const float4 va = ((const float4*)(xi + (r1 << 8)))[j];
            const float4 vb = ((const float4*)(xi + (r2 << 8)))[j];
            const int p4 = s2i(4 * j);
            *(float4*)&w[p4]     = make_float4(va.x, vb.x, va.y, vb.y);
            *(float4*)&w[p4 + 2] = make_float4(va.z, vb.z, va.w, vb.w);
            __builtin_amdgcn_wave_barrier();
            float2 o0, o1, o2, o3;
            fft256<-1>(w, j, tw, o0, o1, o2, o3);
            const int src = (64 - j) & 63;
            float2 P3, P2;
            P3.x = __shfl(o3.x, src); P3.y = __shfl(o3.y, src);   // Z[256-j]
            P2.x = __shfl(o2.x, src); P2.y = __shfl(o2.y, src);   // Z[192-j]
            const float2 Cj = (j == 0) ? make_float2(o0.x, -o0.y)
                                       : make_float2(P3.x, -P3.y);
            const float2 Ck = (j == 0) ? make_float2(P3.x, -P3.y)
                                       : make_float2(P2.x, -P2.y);
            const float2 Aj = make_float2(0.5f * (o0.x + Cj.x), 0.5f * (o0.y + Cj.y));
            const float2 Bj = make_float2(0.5f * (o0.y - Cj.y), -0.5f * (o0.x - Cj.x));
            const float2 Ak = make_float2(0.5f * (o1.x + Ck.x), 0.5f * (o1.y + Ck.y));
            const float2 Bk = make_float2(0.5f * (o1.y - Ck.y), -0.5f * (o1.x - Ck.x));
            S[r1 * 129 + j]      = pack_bf(Aj.x, Aj.y);
            S[r1 * 129 + 64 + j] = pack_bf(Ak.x, Ak.y);
            S[r2 * 129 + j]      = pack_bf(Bj.x, Bj.y);
            S[r2 * 129 + 64 + j] = pack_bf(Bk.x, Bk.y);
            if (j == 0) {
                S[r1 * 129 + 128] = pack_bf(o2.x, 0.0f);
                S[r2 * 129 + 128] = pack_bf(o2.y, 0.0f);
            }
            __builtin_amdgcn_wave_barrier();
        }
    }
    __syncthreads();
    // col phase (radix-16, all 16 waves, 4 cols/wave, cols 16 apart)
    {
        const int g4 = (t >> 4) & 3, l16 = t & 15;
        for (int T = f; T < 33; T += 16) {
            const int cb = (T < 16) ? T : ((T < 32) ? T + 48 : 128);
            const int c = cb + 16 * g4;
            const bool act = (T < 32) || (g4 == 0);
            colfft16<-1>(S, l16, c, act);
        }
    }
    __syncthreads();
    // dump S -> Xf[bo]
    uint4* dst = (uint4*)(Xf + (size_t)bo * 33024);
    const uint4* src4 = (const uint4*)S;
    for (int e = t; e < 8256; e += 1024) dst[e] = src4[e];
}

// --------------------- K2: per-bin einsum (in-place) ------------------------
// Z[b,i,n] = sum_o X[b,o,n] * W[o,i,n], n flat = h*129+w. Block = 32 n (one
// 128B line). rd12 structure (256 thr, depth-2 clamped W prefetch); inner
// product via v_pk_fma_f32 with pair-aligned operands: wp[r] = {w,w}.
__global__ __launch_bounds__(256) void k_einsum(unsigned* __restrict__ Xf,
                                                const float* __restrict__ Wt) {
    __shared__ unsigned xs[512][32];            // [(b<<6)|o][nl] = 64 KB
    const int t = threadIdx.x;
    const int bid = blockIdx.x;                 // 1032 = 8 XCD x 129
    const int nid = (bid & 7) * 129 + (bid >> 3);
    const size_t n0 = (size_t)nid * 32;

#pragma unroll
    for (int k = 0; k < 16; ++k) {
        const int e = t + 256 * k;
        const int pr = e >> 3, q = e & 7;
        const uint4 v = *reinterpret_cast<const uint4*>(
            Xf + (size_t)pr * 33024 + n0 + (q << 2));
        *reinterpret_cast<uint4*>(&xs[pr][q << 2]) = v;
    }
    __syncthreads();

    const int nl = t & 31, j = t >> 5;
    f32x2 acc[8][8];
#pragma unroll
    for (int r = 0; r < 8; ++r)
#pragma unroll
        for (int b = 0; b < 8; ++b) acc[r][b] = (f32x2){0.0f, 0.0f};

    const float* Wb = Wt + n0 + nl;
    auto wload = [&](int o, float (&buf)[8]) {
#pragma unroll
        for (int r = 0; r < 8; ++r)
            buf[r] = __builtin_nontemporal_load(
                Wb + (size_t)((o << 6) | ((r << 3) | j)) * 33024);
    };
    auto fmab = [&](int o, const float (&wc)[8]) {
        f32x2 wp[8];
#pragma unroll
        for (int r = 0; r < 8; ++r) wp[r] = (f32x2){wc[r], wc[r]};
        f32x2 xv[8];
#pragma unroll
        for (int b = 0; b < 8; ++b) {
            const unsigned p = xs[(b << 6) | o][nl];
            f32x2 v;
            v.x = __uint_as_float(p << 16);
            v.y = __uint_as_float(p & 0xffff0000u);
            xv[b] = v;
        }
#pragma unroll
        for (int r = 0; r < 8; ++r)
#pragma unroll
            for (int b = 0; b < 8; ++b) {
                // acc.lo += wp.lo*xv.lo ; acc.hi += wp.hi*xv.hi  (all pairs)
                asm("v_pk_fma_f32 %0, %1, %2, %0"
                    : "+v"(acc[r][b])
                    : "v"(wp[r]), "v"(xv[b]));
            }
    };

    float wA[8], wB[8];
    wload(0, wA);
    wload(1, wB);
    for (int o = 0; o < 64; o += 2) {
        float wc0[8];
#pragma unroll
        for (int r = 0; r < 8; ++r) wc0[r] = wA[r];
        wload(min(o + 2, 63), wA);              // clamped prefetch (tail re-read is L2-hot)
        fmab(o, wc0);
        float wc1[8];
#pragma unroll
        for (int r = 0; r < 8; ++r) wc1[r] = wB[r];
        wload(min(o + 3, 63), wB);
        fmab(o + 1, wc1);
    }

#pragma unroll
    for (int r = 0; r < 8; ++r) {
        const int i = (r << 3) | j;
#pragma unroll
        for (int b = 0; b < 8; ++b) {
            Xf[(size_t)((b << 6) | i) * 33024 + n0 + nl] =
                pack_bf(acc[r][b].x, acc[r][b].y);
        }
    }
}

// ------------- K3: fused col-iFFT + row-irFFT (+bias) per image -------------
__global__ __launch_bounds__(1024) void k_inv2d(const unsigned* __restrict__ Xf,
                                                const float* __restrict__ bias,
                                                float* __restrict__ y) {
    extern __shared__ char smem[];
    unsigned* S = (unsigned*)smem;
    float2* w = (float2*)(smem + 132096) + ((threadIdx.x >> 6) << 8);
    const int t = threadIdx.x, f = t >> 6, j = t & 63;
    const int bo = blockIdx.x;
    const float bv = bias[bo & 63];

    float2 tw[6];
    mk_tw<+1>(j & 3,  0.25f,       tw[0], tw[1]);
    mk_tw<+1>(j & 15, 1.0f/16.0f,  tw[2], tw[3]);
    mk_tw<+1>(j,      1.0f/64.0f,  tw[4], tw[5]);

    const int rbr = (int)(__brev((unsigned)j) >> 26);    // brev6(j)

    // load Xf[bo] -> S
    {
        uint4* s4 = (uint4*)S;
        const uint4* g4p = (const uint4*)(Xf + (size_t)bo * 33024);
        for (int e = t; e < 8256; e += 1024) s4[e] = g4p[e];
    }
    __syncthreads();
    // col inverse phase (radix-16, all 16 waves)
    {
        const int g4 = (t >> 4) & 3, l16 = t & 15;
        for (int T = f; T < 33; T += 16) {
            const int cb = (T < 16) ? T : ((T < 32) ? T + 48 : 128);
            const int c = cb + 16 * g4;
            const bool act = (T < 32) || (g4 == 0);
            colfft16<+1>(S, l16, c, act);
        }
    }
    __syncthreads();
    // row inverse phase (paired, waves 0..14): rd13-verified register-fed
    // round 1 — z built at bit-reversed base m straight from S; k=0,128
    // projected to Re (reference irfft discards their imag content).
    float* yo = y + (size_t)bo * 65536;
    if (f < NWACT) {
        for (int rp = f; rp < 128; rp += NWACT) {
            const int r1 = rp, r2 = rp + 128;
            const unsigned* Sa = S + r1 * 129;
            const unsigned* Sb = S + r2 * 129;
            const int m = rbr;
            const float2 A0 = unpack_bf(Sa[m]),      B0 = unpack_bf(Sb[m]);
            const float2 A1 = unpack_bf(Sa[m + 64]), B1 = unpack_bf(Sb[m + 64]);
            const int i2 = (m == 0) ? 128 : 128 - m;
            const float2 A2 = unpack_bf(Sa[i2]),     B2 = unpack_bf(Sb[i2]);
            const float2 A3 = unpack_bf(Sa[64 - m]), B3 = unpack_bf(Sb[64 - m]);
            // u0 = z(m), u1 = z(m+128), u2 = z(m+64), u3 = z(m+192)
            const float2 u0 = (m == 0)
                ? make_float2(A0.x, B0.x)                                 // k=0 projected
                : make_float2(A0.x - B0.y, A0.y + B0.x);                  // direct
            const float2 u1 = (m == 0)
                ? make_float2(A2.x, B2.x)                                 // k=128 projected
                : make_float2(A2.x + B2.y, B2.x - A2.y);                  // reflected
            const float2 u2 = make_float2(A1.x - B1.y, A1.y + B1.x);      // k=m+64 direct
            const float2 u3 = make_float2(A3.x + B3.y, B3.x - A3.y);      // k=m+192 reflected
            float2 o0, o1, o2, o3;
            fft256_reg<+1>(w, j, tw, u0, u1, u2, u3, o0, o1, o2, o3);
            const float sc = 1.0f / 65536.0f;
            float* y1 = yo + (r1 << 8);
            float* y2 = yo + (r2 << 8);
            __builtin_nontemporal_store(o0.x * sc + bv, y1 + j);
            __builtin_nontemporal_store(o1.x * sc + bv, y1 + j + 64);
            __builtin_nontemporal_store(o2.x * sc + bv, y1 + j + 128);
            __builtin_nontemporal_store(o3.x * sc + bv, y1 + j + 192);
            __builtin_nontemporal_store(o0.y * sc + bv, y2 + j);
            __builtin_nontemporal_store(o1.y * sc + bv, y2 + j + 64);
            __builtin_nontemporal_store(o2.y * sc + bv, y2 + j + 128);
            __builtin_nontemporal_store(o3.y * sc + bv, y2 + j + 192);
            __builtin_amdgcn_wave_barrier();
        }
    }
}

// ---------------------------------------------------------------------------
extern "C" void kernel_launch(void* const* d_in, const int* in_sizes, int n_in,
                              void* d_out, int out_size, void* d_ws,
                              size_t ws_size, hipStream_t stream) {
    (void)in_sizes; (void)n_in; (void)out_size; (void)ws_size;
    const float* x    = (const float*)d_in[0];
    const float* wfft = (const float*)d_in[1];
    const float* bias = (const float*)d_in[2];
    float* y = (float*)d_out;
    unsigned* Xf = (unsigned*)d_ws;             // 512 x 33024 uint = 67.6 MB

    (void)hipFuncSetAttribute((const void*)k_fwd2d,
                        hipFuncAttributeMaxDynamicSharedMemorySize, SMEM_BYTES);
    (void)hipFuncSetAttribute((const void*)k_inv2d,
                        hipFuncAttributeMaxDynamicSharedMemorySize, SMEM_BYTES);

    k_fwd2d<<<512, 1024, SMEM_BYTES, stream>>>(x, Xf);
    k_einsum<<<1032, 256, 0, stream>>>(Xf, wfft);
    k_inv2d<<<512, 1024, SMEM_BYTES, stream>>>(Xf, bias, y);
}